// Round 6
// baseline (356.052 us; speedup 1.0000x reference)
//
#include <hip/hip_runtime.h>
#include <hip/hip_bf16.h>

typedef __attribute__((ext_vector_type(4))) float f32x4;
typedef __attribute__((ext_vector_type(8))) short short8;

#define XROWS 8195            // 3 guard rows + 8192
#define XBATCH (XROWS * 1024) // elems per padded batch

__device__ __forceinline__ short f2bf(float f) {
    union { __hip_bfloat16 h; short s; } u;
    u.h = __float2bfloat16(f);
    return u.s;
}

__device__ __forceinline__ void async16(const void* g, void* l) {
    __builtin_amdgcn_global_load_lds(
        (const __attribute__((address_space(1))) unsigned int*)g,
        (__attribute__((address_space(3))) unsigned int*)l, 16, 0, 0);
}

// ---------------------------------------------------------------------------
// Prepass 1: x fp32 [4][8192][1024] -> Xbf bf16 [4][3+8192][1024], guard=0
// ---------------------------------------------------------------------------
__global__ void x_to_bf16(const float* __restrict__ x,
                          __hip_bfloat16* __restrict__ Xbf) {
    size_t idx = (size_t)blockIdx.x * blockDim.x + threadIdx.x;
    if (idx < 1536) {  // zero 4*3*1024 guard elems
        int b = (int)(idx / 384);
        int r = (int)(idx % 384);
        *reinterpret_cast<short8*>(&Xbf[(size_t)b * XBATCH + r * 8]) =
            (short8){0, 0, 0, 0, 0, 0, 0, 0};
    }
    size_t stride = (size_t)gridDim.x * blockDim.x;
    const size_t nvec = (size_t)4 * 8192 * 1024 / 8;
    for (size_t v = idx; v < nvec; v += stride) {
        size_t e = v * 8;
        int b = (int)(e >> 23);
        size_t rem = e & ((1u << 23) - 1);
        f32x4 lo = *reinterpret_cast<const f32x4*>(x + e);
        f32x4 hi = *reinterpret_cast<const f32x4*>(x + e + 4);
        short8 pk;
        pk[0] = f2bf(lo[0]); pk[1] = f2bf(lo[1]); pk[2] = f2bf(lo[2]); pk[3] = f2bf(lo[3]);
        pk[4] = f2bf(hi[0]); pk[5] = f2bf(hi[1]); pk[6] = f2bf(hi[2]); pk[7] = f2bf(hi[3]);
        *reinterpret_cast<short8*>(&Xbf[(size_t)b * XBATCH + 3 * 1024 + rem]) = pk;
    }
}

// ---------------------------------------------------------------------------
// Prepass 2: kernels [4096][1024] fp32 -> Kt [1024][4096] bf16
// ---------------------------------------------------------------------------
__global__ void kconv_transpose(const float* __restrict__ kern,
                                __hip_bfloat16* __restrict__ Kt) {
    __shared__ float tile[32][33];
    int k0 = blockIdx.x << 5;
    int f0 = blockIdx.y << 5;
    int tx = threadIdx.x & 31;
    int ty = threadIdx.x >> 5;
#pragma unroll
    for (int q = 0; q < 4; q++)
        tile[ty + q * 8][tx] = kern[(size_t)(k0 + ty + q * 8) * 1024 + f0 + tx];
    __syncthreads();
#pragma unroll
    for (int q = 0; q < 4; q++)
        Kt[((size_t)(f0 + ty + q * 8) << 12) + k0 + tx] =
            __float2bfloat16(tile[tx][ty + q * 8]);
}

// ---------------------------------------------------------------------------
// Main GEMM: 128x128 tile, 4 waves (2x2), 2 blocks/CU, K-slice-32 ring.
//   LDS: 4 ring slots x 16KB = 64KB. Slot = 128 lines x 128B
//   (A-row 64B | B-row 64B), XOR-swizzled chunk c ^= (r&7) -> conflict-free
//   reads (0 conflicts measured in both R3 and R4 layouts).
//   Linear DMA dest + inverse-swizzled global source (rule 21).
//   Per phase (128 total): counted vmcnt(8) [never 0] -> s_barrier ->
//   8 ds_read_b128 -> stage slice s+3 (4 async16, depth-3 prefetch) ->
//   16 MFMA under setprio. No sched_barrier pins (m141 lesson).
//   Tail: wrap-around dummy stages into dead slots keep vmcnt uniform.
// ---------------------------------------------------------------------------
__global__ void __launch_bounds__(256, 2)
altconv_gemm6(const __hip_bfloat16* __restrict__ Xbf,  // [4][8195][1024]
              const __hip_bfloat16* __restrict__ Kt,   // [1024][4096]
              const float* __restrict__ biases,        // [4][1024]
              float* __restrict__ out) {               // [32768][1024]
    __shared__ alignas(16) __hip_bfloat16 LS[4 * 8192];  // 64 KiB

    // bijective XCD swizzle (2048 % 8 == 0); nt fastest within an XCD chunk
    int bid  = blockIdx.x;
    int tid2 = (bid & 7) * 256 + (bid >> 3);
    int mt = tid2 >> 3;           // 0..255
    int nt = tid2 & 7;            // 0..7
    int bm0   = mt << 7;
    int batch = bm0 >> 13;
    int srow0 = bm0 & 8191;
    int bn0   = nt << 7;
    const __hip_bfloat16* xb = Xbf + (size_t)batch * XBATCH;
    const __hip_bfloat16* xA = xb + (size_t)(srow0 + 3) * 1024;
    const __hip_bfloat16* bB = Kt + ((size_t)bn0 << 12);

    int t    = threadIdx.x;
    int lane = t & 63;
    int wid  = t >> 6;            // 0..3
    int wr = wid >> 1, wc = wid & 1;
    int frr = lane & 15, q = lane >> 4;
    int swz = (frr & 7) << 4;     // swizzle byte value (line&7 == frr&7)

    // fragment read elem offsets within a slot (line pitch = 64 elems = 128B)
    int aRd[4], bRd[4];
#pragma unroll
    for (int m = 0; m < 4; m++)
        aRd[m] = (wr * 64 + m * 16 + frr) * 64 + ((((q) << 4) ^ swz) >> 1);
#pragma unroll
    for (int n = 0; n < 4; n++)
        bRd[n] = (wc * 64 + n * 16 + frr) * 64 + ((((4 + q) << 4) ^ swz) >> 1);

    // staging precompute: linear DMA dest (wave-contiguous 1KB runs),
    // inverse-swizzled logical source; A/B membership static per thread.
    int  aoff[4], boff[4], ldsE[4];
    bool isA[4];
#pragma unroll
    for (int i = 0; i < 4; i++) {
        int u  = i * 256 + t;          // 16B-chunk index within a slot
        int r  = u >> 3;               // line 0..127
        int cl = (u & 7) ^ (r & 7);    // logical chunk (involution)
        ldsE[i] = u * 8;
        isA[i]  = cl < 4;
        aoff[i] = r * 1024 + cl * 8;          // valid when isA
        boff[i] = r * 4096 + (cl - 4) * 8;    // valid when !isA
    }

    f32x4 acc[4][4];
#pragma unroll
    for (int m = 0; m < 4; m++)
#pragma unroll
        for (int n = 0; n < 4; n++) acc[m][n] = (f32x4){0.f, 0.f, 0.f, 0.f};

#define STAGEP(SLICE, DSTSLOT) do {                                           \
        int ts_  = (SLICE) & 127;                                             \
        int tap_ = ts_ >> 5;                                                  \
        int c0_  = (ts_ & 31) << 5;                                           \
        const __hip_bfloat16* aS_ = xA - tap_ * 1024 + c0_;                   \
        const __hip_bfloat16* bS_ = bB + ts_ * 32;                            \
        _Pragma("unroll")                                                     \
        for (int i = 0; i < 4; i++) {                                         \
            const __hip_bfloat16* p_ =                                        \
                isA[i] ? (aS_ + aoff[i]) : (bS_ + boff[i]);                   \
            async16(p_, &LS[(DSTSLOT) * 8192 + ldsE[i]]);                     \
        }                                                                     \
    } while (0)

#define PHASE(SLOT, DSTSLOT, SLICE) do {                                      \
        asm volatile("s_waitcnt vmcnt(8)" ::: "memory");                      \
        __builtin_amdgcn_s_barrier();                                         \
        asm volatile("" ::: "memory");                                        \
        short8 af[4], bf4[4];                                                 \
        _Pragma("unroll")                                                     \
        for (int m = 0; m < 4; m++)                                           \
            af[m] = *reinterpret_cast<const short8*>(                         \
                &LS[(SLOT) * 8192 + aRd[m]]);                                 \
        _Pragma("unroll")                                                     \
        for (int n = 0; n < 4; n++)                                           \
            bf4[n] = *reinterpret_cast<const short8*>(                        \
                &LS[(SLOT) * 8192 + bRd[n]]);                                 \
        STAGEP(SLICE, DSTSLOT);                                               \
        __builtin_amdgcn_s_setprio(1);                                        \
        _Pragma("unroll")                                                     \
        for (int m = 0; m < 4; m++)                                           \
            _Pragma("unroll")                                                 \
            for (int n = 0; n < 4; n++)                                       \
                acc[m][n] = __builtin_amdgcn_mfma_f32_16x16x32_bf16(          \
                    af[m], bf4[n], acc[m][n], 0, 0, 0);                       \
        __builtin_amdgcn_s_setprio(0);                                        \
    } while (0)

    // prologue: stage slices 0,1,2 into slots 0,1,2 (12 loads in flight)
    STAGEP(0, 0);
    STAGEP(1, 1);
    STAGEP(2, 2);

    for (int it = 0; it < 32; ++it) {
        int s0 = it << 2;
        PHASE(0, 3, s0 + 3);
        PHASE(1, 0, s0 + 4);
        PHASE(2, 1, s0 + 5);
        PHASE(3, 2, s0 + 6);
    }

    // epilogue: C/D layout col=lane&15, row=(lane>>4)*4+j  [m89]
    int fr   = lane & 15;
    int rowg = (lane >> 4) << 2;
#pragma unroll
    for (int n = 0; n < 4; n++) {
        int gc = bn0 + wc * 64 + n * 16 + fr;
        float bsum = biases[gc] + biases[1024 + gc] + biases[2048 + gc] + biases[3072 + gc];
#pragma unroll
        for (int m = 0; m < 4; m++) {
            size_t gr = (size_t)(bm0 + wr * 64 + m * 16 + rowg);
#pragma unroll
            for (int j = 0; j < 4; j++) {
                out[(gr + j) * 1024 + gc] = acc[m][n][j] + bsum;
            }
        }
    }
#undef STAGEP
#undef PHASE
}

// ---------------------------------------------------------------------------
// Fallback: plain fp32 (no workspace needed), correct but slow
// ---------------------------------------------------------------------------
__global__ void fallback_conv(const float* __restrict__ x, const float* __restrict__ kern,
                              const float* __restrict__ biases, float* __restrict__ out) {
    __shared__ float xs[1024];
    int row = blockIdx.x;
    int f = (blockIdx.y << 8) + threadIdx.x;
    int batch = row >> 13, s = row & 8191;
    const float* xb = x + (((size_t)batch << 13) << 10);
    float acc = 0.f;
    for (int tap = 0; tap < 4; tap++) {
        int ss = s - tap;
        __syncthreads();
        for (int i = threadIdx.x; i < 1024; i += 256)
            xs[i] = (ss >= 0) ? xb[((size_t)ss << 10) + i] : 0.f;
        __syncthreads();
        const float* kp = kern + ((size_t)tap << 20) + f;
        float a = 0.f;
        for (int d = 0; d < 1024; d++) a += xs[d] * kp[(size_t)d << 10];
        acc += a + biases[(tap << 10) + f];
    }
    out[((size_t)row << 10) + f] = acc;
}

extern "C" void kernel_launch(void* const* d_in, const int* in_sizes, int n_in,
                              void* d_out, int out_size, void* d_ws, size_t ws_size,
                              hipStream_t stream) {
    const float* x      = (const float*)d_in[0];
    const float* kern   = (const float*)d_in[1];
    const float* biases = (const float*)d_in[2];
    float* out = (float*)d_out;

    const size_t xbf_bytes = (size_t)4 * XBATCH * sizeof(__hip_bfloat16); // 67.1 MB
    const size_t kt_bytes  = (size_t)4096 * 1024 * sizeof(__hip_bfloat16); // 8.4 MB

    if (ws_size >= xbf_bytes + kt_bytes) {
        __hip_bfloat16* Xbf = (__hip_bfloat16*)d_ws;
        __hip_bfloat16* Kt  = (__hip_bfloat16*)((char*)d_ws + xbf_bytes);
        x_to_bf16<<<2048, 256, 0, stream>>>(x, Xbf);
        kconv_transpose<<<dim3(128, 32), 256, 0, stream>>>(kern, Kt);
        altconv_gemm6<<<2048, 256, 0, stream>>>(Xbf, Kt, biases, out);
    } else {
        fallback_conv<<<dim3(32768, 4), 256, 0, stream>>>(x, kern, biases, out);
    }
}

// Round 7
// 264.096 us; speedup vs baseline: 1.3482x; 1.3482x over previous
//
#include <hip/hip_runtime.h>
#include <hip/hip_bf16.h>

typedef __attribute__((ext_vector_type(4))) float f32x4;
typedef __attribute__((ext_vector_type(8))) short short8;

#define XROWS 8195            // 3 guard rows + 8192
#define XBATCH (XROWS * 1024) // elems per padded batch

__device__ __forceinline__ short f2bf(float f) {
    union { __hip_bfloat16 h; short s; } u;
    u.h = __float2bfloat16(f);
    return u.s;
}

__device__ __forceinline__ void async16(const void* g, void* l) {
    __builtin_amdgcn_global_load_lds(
        (const __attribute__((address_space(1))) unsigned int*)g,
        (__attribute__((address_space(3))) unsigned int*)l, 16, 0, 0);
}

// ---------------------------------------------------------------------------
// Prepass 1: x fp32 [4][8192][1024] -> Xbf bf16 [4][3+8192][1024], guard=0
// ---------------------------------------------------------------------------
__global__ void x_to_bf16(const float* __restrict__ x,
                          __hip_bfloat16* __restrict__ Xbf) {
    size_t idx = (size_t)blockIdx.x * blockDim.x + threadIdx.x;
    if (idx < 1536) {  // zero 4*3*1024 guard elems
        int b = (int)(idx / 384);
        int r = (int)(idx % 384);
        *reinterpret_cast<short8*>(&Xbf[(size_t)b * XBATCH + r * 8]) =
            (short8){0, 0, 0, 0, 0, 0, 0, 0};
    }
    size_t stride = (size_t)gridDim.x * blockDim.x;
    const size_t nvec = (size_t)4 * 8192 * 1024 / 8;
    for (size_t v = idx; v < nvec; v += stride) {
        size_t e = v * 8;
        int b = (int)(e >> 23);
        size_t rem = e & ((1u << 23) - 1);
        f32x4 lo = *reinterpret_cast<const f32x4*>(x + e);
        f32x4 hi = *reinterpret_cast<const f32x4*>(x + e + 4);
        short8 pk;
        pk[0] = f2bf(lo[0]); pk[1] = f2bf(lo[1]); pk[2] = f2bf(lo[2]); pk[3] = f2bf(lo[3]);
        pk[4] = f2bf(hi[0]); pk[5] = f2bf(hi[1]); pk[6] = f2bf(hi[2]); pk[7] = f2bf(hi[3]);
        *reinterpret_cast<short8*>(&Xbf[(size_t)b * XBATCH + 3 * 1024 + rem]) = pk;
    }
}

// ---------------------------------------------------------------------------
// Prepass 2: kernels [4096][1024] fp32 -> Kt [1024][4096] bf16
// ---------------------------------------------------------------------------
__global__ void kconv_transpose(const float* __restrict__ kern,
                                __hip_bfloat16* __restrict__ Kt) {
    __shared__ float tile[32][33];
    int k0 = blockIdx.x << 5;
    int f0 = blockIdx.y << 5;
    int tx = threadIdx.x & 31;
    int ty = threadIdx.x >> 5;
#pragma unroll
    for (int q = 0; q < 4; q++)
        tile[ty + q * 8][tx] = kern[(size_t)(k0 + ty + q * 8) * 1024 + f0 + tx];
    __syncthreads();
#pragma unroll
    for (int q = 0; q < 4; q++)
        Kt[((size_t)(f0 + ty + q * 8) << 12) + k0 + tx] =
            __float2bfloat16(tile[tx][ty + q * 8]);
}

// ---------------------------------------------------------------------------
// Main GEMM — m201-style 8-phase 256^2 template:
//   BM=BN=256, BK=64, 8 waves (2M x 4N), wave tile 128x64, 512 threads.
//   LDS 128 KiB = 2-tile dbuf x (A 32KB + B 32KB).
//   8 phases / 2 K-tiles; phase = one C-quadrant (h,ks): 4 A ds_reads
//   (+4 B on ks-change), 1 half-tile stage (4 async16), 1 barrier,
//   16 MFMA under setprio. Counted vmcnt(4) at phases 1 & 5 only
//   (1 half-tile stays in flight; >=3-phase issue->read cover).
//   XOR swizzle byte^=((row&7)<<4), linear DMA dest + inverse-swizzled
//   source (rule 21). Stage halves match quadrant row sets so every
//   LDS region is overwritten >=1 barrier after its last read.
// ---------------------------------------------------------------------------
__global__ void __launch_bounds__(512, 2)
altconv_gemm7(const __hip_bfloat16* __restrict__ Xbf,  // [4][8195][1024]
              const __hip_bfloat16* __restrict__ Kt,   // [1024][4096]
              const float* __restrict__ biases,        // [4][1024]
              float* __restrict__ out) {               // [32768][1024]
    __shared__ alignas(16) __hip_bfloat16 LS[65536];   // 128 KiB

    // bijective XCD swizzle (512 % 8 == 0); nt fastest within an XCD chunk
    int bid  = blockIdx.x;
    int tid2 = (bid & 7) * 64 + (bid >> 3);
    int mt = tid2 >> 2;           // 0..127
    int nt = tid2 & 3;            // 0..3
    int bm0   = mt << 8;
    int batch = bm0 >> 13;
    int srow0 = bm0 & 8191;
    int bn0   = nt << 8;
    const __hip_bfloat16* xb = Xbf + (size_t)batch * XBATCH;

    int t    = threadIdx.x;
    int lane = t & 63;
    int wid  = t >> 6;            // 0..7
    int wr = wid >> 2, wc = wid & 3;
    int frr = lane & 15, q = lane >> 4;
    int swz = (frr & 7) << 4;

    // fragment read elem offsets (row pitch 64 elems = 128B)
    // A: row = wr*128 + h*64 + m*16 + frr   (region: 256 rows)
    // B: row = wc*64  + n*16 + frr          (region: 256 rows)
    int aRd[2][4][2], bRd[4][2];
#pragma unroll
    for (int h = 0; h < 2; h++)
#pragma unroll
        for (int m = 0; m < 4; m++) {
            int row = wr * 128 + h * 64 + m * 16 + frr;
#pragma unroll
            for (int ks = 0; ks < 2; ks++)
                aRd[h][m][ks] = row * 64 + (((ks * 64 + (q << 4)) ^ swz) >> 1);
        }
#pragma unroll
    for (int n = 0; n < 4; n++) {
        int row = wc * 64 + n * 16 + frr;
#pragma unroll
        for (int ks = 0; ks < 2; ks++)
            bRd[n][ks] = row * 64 + (((ks * 64 + (q << 4)) ^ swz) >> 1);
    }

    // staging precompute (per thread, 2 chunks per half):
    // u in [0,1024): rr = u>>3 (0..127), c = u&7.
    // A half HF rows: HF=0 -> {[0,64) u [128,192)}, HF=1 -> +64 (quadrant rows)
    // B half HF rows: HF*128 + rr.
    int srcA[2], dstA[2], srcB[2], dstB[2];
#pragma unroll
    for (int ld = 0; ld < 2; ld++) {
        int u  = ld * 512 + t;
        int rr = u >> 3;
        int c  = u & 7;
        int growA = (rr < 64) ? rr : rr + 64;           // HF=0 base
        dstA[ld] = growA * 8 + c;                       // chunk in A region
        srcA[ld] = growA * 1024 + ((c ^ (growA & 7)) * 8);
        dstB[ld] = rr * 8 + c;                          // + HF*1024
        srcB[ld] = rr * 4096 + ((c ^ (rr & 7)) * 8);    // + HF row-base via ptr
    }

    f32x4 acc[2][4][4];
#pragma unroll
    for (int h = 0; h < 2; h++)
#pragma unroll
        for (int m = 0; m < 4; m++)
#pragma unroll
            for (int n = 0; n < 4; n++) acc[h][m][n] = (f32x4){0.f, 0.f, 0.f, 0.f};

    // STAGEH(T, HF): stage A-half + B-half of tile T (4 async16)
#define STAGEH(T, HF) do {                                                    \
        int tap_ = (T) >> 4;                                                  \
        int d0_  = ((T) & 15) << 6;                                           \
        int pA_  = ((T) & 1) << 15;  /* buf elem base: 0 or 32768 */          \
        const __hip_bfloat16* xT_ =                                           \
            xb + (size_t)(srow0 + 3 - tap_) * 1024 + d0_ + (HF) * 65536;      \
        const __hip_bfloat16* bT_ =                                           \
            Kt + (((size_t)(bn0 + (HF) * 128)) << 12) + (T) * 64;             \
        _Pragma("unroll")                                                     \
        for (int ld = 0; ld < 2; ld++)                                        \
            async16(xT_ + srcA[ld], &LS[pA_ + (dstA[ld] + (HF) * 512) * 8]);  \
        _Pragma("unroll")                                                     \
        for (int ld = 0; ld < 2; ld++)                                        \
            async16(bT_ + srcB[ld],                                           \
                    &LS[pA_ + 16384 + (dstB[ld] + (HF) * 1024) * 8]);         \
    } while (0)

    short8 bfr[4];

    // PH(P,H,KS,RB,WAIT,STG,STGT,STGHF): one phase.
#define PH(P, H, KS, RB, WAIT, STG, STGT, STGHF) do {                         \
        if ((WAIT) == 4) asm volatile("s_waitcnt vmcnt(4)" ::: "memory");     \
        else if ((WAIT) == 0) asm volatile("s_waitcnt vmcnt(0)" ::: "memory");\
        __builtin_amdgcn_s_barrier();                                         \
        asm volatile("" ::: "memory");                                        \
        short8 af[4];                                                         \
        _Pragma("unroll")                                                     \
        for (int m = 0; m < 4; m++)                                           \
            af[m] = *reinterpret_cast<const short8*>(                         \
                &LS[((P) << 15) + aRd[H][m][KS]]);                            \
        if (RB) {                                                             \
            _Pragma("unroll")                                                 \
            for (int n = 0; n < 4; n++)                                       \
                bfr[n] = *reinterpret_cast<const short8*>(                    \
                    &LS[((P) << 15) + 16384 + bRd[n][KS]]);                   \
        }                                                                     \
        if (STG) STAGEH(STGT, STGHF);                                         \
        __builtin_amdgcn_s_setprio(1);                                        \
        _Pragma("unroll")                                                     \
        for (int m = 0; m < 4; m++)                                           \
            _Pragma("unroll")                                                 \
            for (int n = 0; n < 4; n++)                                       \
                acc[H][m][n] = __builtin_amdgcn_mfma_f32_16x16x32_bf16(       \
                    af[m], bfr[n], acc[H][m][n], 0, 0, 0);                    \
        __builtin_amdgcn_s_setprio(0);                                        \
    } while (0)

    // prologue: T0 both halves, T1 half0 (12 loads in flight)
    STAGEH(0, 0);
    STAGEH(0, 1);
    STAGEH(1, 0);

    for (int I = 0; I < 31; ++I) {
        int T1 = 2 * I + 1, T2 = 2 * I + 2, T3 = 2 * I + 3;
        PH(0, 0, 0, 1, 4, 1, T1, 1);   // wait T0-class done; stage odd.HF1
        PH(0, 1, 0, 0, -1, 0, 0, 0);
        PH(0, 0, 1, 1, -1, 0, 0, 0);
        PH(0, 1, 1, 0, -1, 1, T2, 0);  // even+2 half0 (rows free after ph3)
        PH(1, 0, 0, 1, 4, 1, T2, 1);   // wait odd done; even+2 half1
        PH(1, 1, 0, 0, -1, 0, 0, 0);
        PH(1, 0, 1, 1, -1, 0, 0, 0);
        PH(1, 1, 1, 0, -1, 1, T3, 0);  // odd+2 half0
    }
    // epilogue super: tiles 62 (buf0), 63 (buf1); finish 63.HF1, then drain
    PH(0, 0, 0, 1, 4, 1, 63, 1);
    PH(0, 1, 0, 0, -1, 0, 0, 0);
    PH(0, 0, 1, 1, -1, 0, 0, 0);
    PH(0, 1, 1, 0, -1, 0, 0, 0);
    PH(1, 0, 0, 1, 0, 0, 0, 0);        // vmcnt(0): tile 63 fully landed
    PH(1, 1, 0, 0, -1, 0, 0, 0);
    PH(1, 0, 1, 1, -1, 0, 0, 0);
    PH(1, 1, 1, 0, -1, 0, 0, 0);

    // epilogue: C/D layout col=lane&15, row=(lane>>4)*4+j  [m89]
    int fr   = lane & 15;
    int rowg = (lane >> 4) << 2;
#pragma unroll
    for (int n = 0; n < 4; n++) {
        int gc = bn0 + wc * 64 + n * 16 + fr;
        float bsum = biases[gc] + biases[1024 + gc] + biases[2048 + gc] + biases[3072 + gc];
#pragma unroll
        for (int h = 0; h < 2; h++)
#pragma unroll
            for (int m = 0; m < 4; m++) {
                size_t gr = (size_t)(bm0 + wr * 128 + h * 64 + m * 16 + rowg);
#pragma unroll
                for (int j = 0; j < 4; j++) {
                    out[(gr + j) * 1024 + gc] = acc[h][m][n][j] + bsum;
                }
            }
    }
#undef STAGEH
#undef PH
}

// ---------------------------------------------------------------------------
// Fallback: plain fp32 (no workspace needed), correct but slow
// ---------------------------------------------------------------------------
__global__ void fallback_conv(const float* __restrict__ x, const float* __restrict__ kern,
                              const float* __restrict__ biases, float* __restrict__ out) {
    __shared__ float xs[1024];
    int row = blockIdx.x;
    int f = (blockIdx.y << 8) + threadIdx.x;
    int batch = row >> 13, s = row & 8191;
    const float* xb = x + (((size_t)batch << 13) << 10);
    float acc = 0.f;
    for (int tap = 0; tap < 4; tap++) {
        int ss = s - tap;
        __syncthreads();
        for (int i = threadIdx.x; i < 1024; i += 256)
            xs[i] = (ss >= 0) ? xb[((size_t)ss << 10) + i] : 0.f;
        __syncthreads();
        const float* kp = kern + ((size_t)tap << 20) + f;
        float a = 0.f;
        for (int d = 0; d < 1024; d++) a += xs[d] * kp[(size_t)d << 10];
        acc += a + biases[(tap << 10) + f];
    }
    out[((size_t)row << 10) + f] = acc;
}

extern "C" void kernel_launch(void* const* d_in, const int* in_sizes, int n_in,
                              void* d_out, int out_size, void* d_ws, size_t ws_size,
                              hipStream_t stream) {
    const float* x      = (const float*)d_in[0];
    const float* kern   = (const float*)d_in[1];
    const float* biases = (const float*)d_in[2];
    float* out = (float*)d_out;

    const size_t xbf_bytes = (size_t)4 * XBATCH * sizeof(__hip_bfloat16); // 67.1 MB
    const size_t kt_bytes  = (size_t)4096 * 1024 * sizeof(__hip_bfloat16); // 8.4 MB

    if (ws_size >= xbf_bytes + kt_bytes) {
        __hip_bfloat16* Xbf = (__hip_bfloat16*)d_ws;
        __hip_bfloat16* Kt  = (__hip_bfloat16*)((char*)d_ws + xbf_bytes);
        x_to_bf16<<<2048, 256, 0, stream>>>(x, Xbf);
        kconv_transpose<<<dim3(128, 32), 256, 0, stream>>>(kern, Kt);
        altconv_gemm7<<<512, 512, 0, stream>>>(Xbf, Kt, biases, out);
    } else {
        fallback_conv<<<dim3(32768, 4), 256, 0, stream>>>(x, kern, biases, out);
    }
}